// Round 1
// baseline (729.072 us; speedup 1.0000x reference)
//
#include <hip/hip_runtime.h>

#define GN    128
#define GBIG  1.0e5f
#define NITER 128

// Padded layout: x pitch 128, y and z padded to 130 with BIG boundary planes.
#define PPY     130
#define PITCH_Y 128
#define PITCH_Z (128 * 130)
#define PADDED_TOTAL (130 * 130 * 128)

// Persistent-kernel block grid: tile 128 x 8 x 2  ->  16 x 64 blocks
#define NBY  16
#define NBZ  64
#define NBLK (NBY * NBZ)

typedef float fx4 __attribute__((ext_vector_type(4)));

// ---------------------------------------------------------------------------
// init: build padded uA, uB (both! culled regions rely on init values), fP,
// and zero the per-block iteration flags.
// ---------------------------------------------------------------------------
__global__ __launch_bounds__(256) void eik_init(const float* __restrict__ u0,
                                                const float* __restrict__ f,
                                                float* __restrict__ uA,
                                                float* __restrict__ uB,
                                                float* __restrict__ fP,
                                                int* __restrict__ flags) {
    const int i = blockIdx.x * 256 + threadIdx.x;
    if (i < NBLK) flags[i] = 0;
    if (i >= PADDED_TOTAL) return;
    const int x = i & 127;
    const int r = i >> 7;          // r = z*130 + y
    const int y = r % 130;
    const int z = r / 130;
    float uv = GBIG, fv = 0.0f;
    if (y >= 1 && y <= GN && z >= 1 && z <= GN) {
        const int src = ((z - 1) * GN + (y - 1)) * GN + x;
        uv = u0[src];
        fv = f[src];
    }
    uA[i] = uv;
    uB[i] = uv;
    fP[i] = fv;
}

// ---------------------------------------------------------------------------
// local upwind eikonal solve (identical arithmetic to reference)
// ---------------------------------------------------------------------------
__device__ __forceinline__ float eik_solve(float ax, float ay, float az,
                                           float fh, float uc) {
    const float a1 = fminf(fminf(ax, ay), az);
    const float a3 = fmaxf(fmaxf(ax, ay), az);
    const float a2 = fmaxf(fminf(fmaxf(ax, ay), az), fminf(ax, ay));
    const float x1 = a1 + fh;
    const float d12 = a1 - a2;
    const float disc2 = 2.0f * fh * fh - d12 * d12;
    const float x2 = 0.5f * (a1 + a2 + sqrtf(fmaxf(disc2, 0.0f)));
    const float s = a1 + a2 + a3;
    const float q = a1 * a1 + a2 * a2 + a3 * a3;
    const float disc3 = s * s - 3.0f * (q - fh * fh);
    const float x3 = (s + sqrtf(fmaxf(disc3, 0.0f))) * (1.0f / 3.0f);
    const float xv = (x1 <= a2) ? x1 : ((x2 <= a3) ? x2 : x3);
    return fminf(uc, xv);
}

// ---------------------------------------------------------------------------
// persistent cooperative kernel: all 128 Jacobi sweeps in ONE dispatch.
// Tile 128x8x2 per block; u-center + f live in registers for the whole run.
// Cross-block sync: per-block iteration flags (AGENT atomics), neighbor-only
// (y±1, z±1) spin — allows pipelining slack instead of a global barrier.
// All u halo traffic uses sc0 sc1 (device-coherent, L3-served) so per-XCD L2
// staleness cannot bite; flag publish is ordered by per-wave vmcnt(0) +
// __syncthreads.  Protocol: flag[b]==i  <=>  block b's u_i is stored AND b is
// done reading iteration i-1 data (covers both RAW and the ping-pong
// anti-dependency: writer of buf[i&1] waits neighbors >= i-1, which implies
// they finished reading u_{i-2} from that same buffer).
// ---------------------------------------------------------------------------
__global__ __launch_bounds__(256, 4) void eik_persist(float* __restrict__ uA,
                                                      float* __restrict__ uB,
                                                      const float* __restrict__ fP,
                                                      float* __restrict__ out,
                                                      int* __restrict__ flags) {
    const int lx = threadIdx.x;        // 0..31, 4 x-cells each
    const int ty = threadIdx.y;        // 0..7
    const int by = blockIdx.y;         // 0..15
    const int bz = blockIdx.z;         // 0..63
    const int tid = ty * 32 + lx;
    const int gy  = by * 8 + ty;       // 0..127
    const int gz0 = bz * 2;            // plane pair gz0, gz0+1
    const int x0  = lx * 4;

    // exact active-set cull distances (same criterion as the reference loop)
    const int dxm = (x0 <= 64 && 64 <= x0 + 3) ? 0
                                               : min(abs(x0 - 64), abs(x0 + 3 - 64));
    const int dy = abs(gy - 64);
    const int d0 = dxm + dy + abs(gz0 - 64);
    const int d1 = dxm + dy + abs(gz0 + 1 - 64);

    // block activation iteration (min L1 distance over the whole tile; x spans
    // the source column so dxm_min = 0)
    const int ry0 = by * 8, ry1 = ry0 + 7;
    const int dymin = (ry0 > 64) ? (ry0 - 64) : ((ry1 < 64) ? (64 - ry1) : 0);
    const int dzmin = (gz0 > 64) ? (gz0 - 64) : ((gz0 + 1 < 64) ? (64 - (gz0 + 1)) : 0);
    const int start = max(1, dymin + dzmin);

    const int idx = bz * NBY + by;
    if (tid == 0 && start > 1)   // pre-publish: u_{start-1} == u_0, already in both buffers
        __hip_atomic_store(&flags[idx], start - 1, __ATOMIC_RELAXED,
                           __HIP_MEMORY_SCOPE_AGENT);

    const int base0 = ((gz0 + 1) * PPY + (gy + 1)) * PITCH_Y + x0;
    const int base1 = base0 + PITCH_Z;
    const int vo0  = base0 * 4;               // byte voffsets for saddr-form vmem
    const int vo1  = base1 * 4;
    const int vozm = vo0 - PITCH_Z * 4;       // plane gz0-1 (pad plane when gz0==0)
    const int vozp = vo1 + PITCH_Z * 4;       // plane gz0+2 (pad plane when gz0==126)

    // neighbor flag byte offsets; missing neighbors alias our OWN flag (always
    // == i-1 at wait time, so trivially satisfied)
    const int own = idx * 4;
    const int fo0 = (by > 0)       ? own - 4       : own;
    const int fo1 = (by < NBY - 1) ? own + 4       : own;
    const int fo2 = (bz > 0)       ? own - 4 * NBY : own;
    const int fo3 = (bz < NBZ - 1) ? own + 4 * NBY : own;

    // resident state: u-center and f for both planes (u_0 from init)
    fx4 c0 = *(const fx4*)(uA + base0);
    fx4 c1 = *(const fx4*)(uA + base1);
    const fx4 f0 = *(const fx4*)(fP + base0);
    const fx4 f1 = *(const fx4*)(fP + base1);

    int s0 = 0, s1 = 0, s2 = 0, s3 = 0;   // cached neighbor flags (monotone)

    for (int i = start; i <= NITER; ++i) {
        const int target = i - 1;

        // ---- wait: 4 neighbor flags >= i-1 (wave 0 only; others park) ----
        if (tid < 64) {
            int m = min(min(s0, s1), min(s2, s3));
            while (m < target) {
                asm volatile(
                    "global_load_dword %0, %4, %8 sc0 sc1\n\t"
                    "global_load_dword %1, %5, %8 sc0 sc1\n\t"
                    "global_load_dword %2, %6, %8 sc0 sc1\n\t"
                    "global_load_dword %3, %7, %8 sc0 sc1\n\t"
                    "s_waitcnt vmcnt(0)"
                    : "=&v"(s0), "=&v"(s1), "=&v"(s2), "=&v"(s3)
                    : "v"(fo0), "v"(fo1), "v"(fo2), "v"(fo3), "s"(flags)
                    : "memory");
                m = min(min(s0, s1), min(s2, s3));
                if (m < target) {
                    if (target - m > 2) __builtin_amdgcn_s_sleep(32);
                    else                __builtin_amdgcn_s_sleep(1);
                }
            }
        }
        __syncthreads();

        // ---- coherent halo loads from the u_{i-1} buffer ----
        const float* S = (i & 1) ? uA : uB;
        fx4 ym0, yp0, ym1, yp1, zm, zp;
        asm volatile(
            "global_load_dwordx4 %0, %6, %10 offset:-512 sc0 sc1\n\t"
            "global_load_dwordx4 %1, %6, %10 offset:512 sc0 sc1\n\t"
            "global_load_dwordx4 %2, %7, %10 offset:-512 sc0 sc1\n\t"
            "global_load_dwordx4 %3, %7, %10 offset:512 sc0 sc1\n\t"
            "global_load_dwordx4 %4, %8, %10 sc0 sc1\n\t"
            "global_load_dwordx4 %5, %9, %10 sc0 sc1\n\t"
            "s_waitcnt vmcnt(0)"
            : "=&v"(ym0), "=&v"(yp0), "=&v"(ym1), "=&v"(yp1), "=&v"(zm), "=&v"(zp)
            : "v"(vo0), "v"(vo1), "v"(vozm), "v"(vozp), "s"(S)
            : "memory");

        // ---- x-neighbors via intra-wave shuffle of register centers ----
        float xm0 = __shfl_up(c0.w, 1);   if (lx == 0)  xm0 = GBIG;
        float xp0 = __shfl_down(c0.x, 1); if (lx == 31) xp0 = GBIG;
        float xm1 = __shfl_up(c1.w, 1);   if (lx == 0)  xm1 = GBIG;
        float xp1 = __shfl_down(c1.x, 1); if (lx == 31) xp1 = GBIG;

        // ---- local solves (plane0: zp is c1 in-register; plane1: zm is c0) ----
        fx4 n0, n1;
        n0.x = eik_solve(fminf(xm0,  c0.y), fminf(ym0.x, yp0.x), fminf(zm.x, c1.x), f0.x, c0.x);
        n0.y = eik_solve(fminf(c0.x, c0.z), fminf(ym0.y, yp0.y), fminf(zm.y, c1.y), f0.y, c0.y);
        n0.z = eik_solve(fminf(c0.y, c0.w), fminf(ym0.z, yp0.z), fminf(zm.z, c1.z), f0.z, c0.z);
        n0.w = eik_solve(fminf(c0.z, xp0),  fminf(ym0.w, yp0.w), fminf(zm.w, c1.w), f0.w, c0.w);
        n1.x = eik_solve(fminf(xm1,  c1.y), fminf(ym1.x, yp1.x), fminf(c0.x, zp.x), f1.x, c1.x);
        n1.y = eik_solve(fminf(c1.x, c1.z), fminf(ym1.y, yp1.y), fminf(c0.y, zp.y), f1.y, c1.y);
        n1.z = eik_solve(fminf(c1.y, c1.w), fminf(ym1.z, yp1.z), fminf(c0.z, zp.z), f1.z, c1.z);
        n1.w = eik_solve(fminf(c1.z, xp1),  fminf(ym1.w, yp1.w), fminf(c0.w, zp.w), f1.w, c1.w);

        const bool act0 = (d0 <= i);
        const bool act1 = (d1 <= i);

        if (i < NITER) {
            float* D = (i & 1) ? uB : uA;
            if (act0) {
                c0 = n0;
                asm volatile("global_store_dwordx4 %0, %1, %2 sc0 sc1"
                             :: "v"(vo0), "v"(c0), "s"(D) : "memory");
            }
            if (act1) {
                c1 = n1;
                asm volatile("global_store_dwordx4 %0, %1, %2 sc0 sc1"
                             :: "v"(vo1), "v"(c1), "s"(D) : "memory");
            }
            asm volatile("s_waitcnt vmcnt(0)" ::: "memory");  // wave's stores at coherent point
            __syncthreads();                                   // all waves' stores done
            if (tid == 0)
                __hip_atomic_store(&flags[idx], i, __ATOMIC_RELAXED,
                                   __HIP_MEMORY_SCOPE_AGENT);
        } else {
            // final sweep: nobody reads u_128 from the buffers — keep in regs
            if (act0) c0 = n0;
            if (act1) c1 = n1;
        }
    }

    // fused extract: write compact 128^3 output directly from registers
    float* o = out + (gz0 * GN + gy) * GN + x0;
    *(fx4*)o = c0;
    *(fx4*)(o + GN * GN) = c1;
}

// ---------------------------------------------------------------------------
// fallback path (previous proven 128-launch structure), kept in case the
// cooperative launch is unavailable under graph capture
// ---------------------------------------------------------------------------
__global__ __launch_bounds__(256) void eik_step(const float* __restrict__ uin,
                                                const float* __restrict__ fP,
                                                float* __restrict__ uout,
                                                int iter) {
    const int lx = threadIdx.x;
    const int gy = blockIdx.y * 8 + threadIdx.y;
    const int gz = blockIdx.z;
    const int x0 = 4 * lx;
    const int dxm = (x0 <= 64 && 64 <= x0 + 3)
                        ? 0
                        : min(abs(x0 - 64), abs(x0 + 3 - 64));
    const int d = dxm + abs(gy - 64) + abs(gz - 64);
    if (d > iter) return;

    const int y = gy + 1;
    const int z = gz + 1;
    const int base = (z * PPY + y) * PITCH_Y + x0;

    const float4 c  = *(const float4*)(uin + base);
    float xm_s = uin[base - 1];
    float xp_s = uin[base + 4];
    if (lx == 0)  xm_s = GBIG;
    if (lx == 31) xp_s = GBIG;
    const float4 ym = *(const float4*)(uin + base - PITCH_Y);
    const float4 yp = *(const float4*)(uin + base + PITCH_Y);
    const float4 zm = *(const float4*)(uin + base - PITCH_Z);
    const float4 zp = *(const float4*)(uin + base + PITCH_Z);
    const float4 f4 = *(const float4*)(fP + base);

    float4 res;
    res.x = eik_solve(fminf(xm_s, c.y), fminf(ym.x, yp.x), fminf(zm.x, zp.x), f4.x, c.x);
    res.y = eik_solve(fminf(c.x, c.z), fminf(ym.y, yp.y), fminf(zm.y, zp.y), f4.y, c.y);
    res.z = eik_solve(fminf(c.y, c.w), fminf(ym.z, yp.z), fminf(zm.z, zp.z), f4.z, c.z);
    res.w = eik_solve(fminf(c.z, xp_s), fminf(ym.w, yp.w), fminf(zm.w, zp.w), f4.w, c.w);

    *(float4*)(uout + base) = res;
}

__global__ __launch_bounds__(256) void eik_extract(const float* __restrict__ uf,
                                                   float* __restrict__ out) {
    const int j = blockIdx.x * 256 + threadIdx.x;
    const int x4 = j & 31;
    const int y  = (j >> 5) & 127;
    const int z  = j >> 12;
    const float4 v =
        *(const float4*)(uf + ((z + 1) * PPY + (y + 1)) * PITCH_Y + 4 * x4);
    *(float4*)(out + 4 * j) = v;
}

extern "C" void kernel_launch(void* const* d_in, const int* in_sizes, int n_in,
                              void* d_out, int out_size, void* d_ws, size_t ws_size,
                              hipStream_t stream) {
    const float* u0 = (const float*)d_in[0];
    const float* f  = (const float*)d_in[1];
    float* out = (float*)d_out;

    float* uA = (float*)d_ws;                    // 8.65 MB each
    float* uB = uA + PADDED_TOTAL;
    float* fP = uB + PADDED_TOTAL;
    int* flags = (int*)(fP + PADDED_TOTAL);      // 4 KB per-block iteration flags

    {
        const int nb = (PADDED_TOTAL + 255) / 256;
        eik_init<<<nb, 256, 0, stream>>>(u0, f, uA, uB, fP, flags);
    }

    // cooperative co-residency pre-check (pure host query, capture-safe),
    // cached across graph replays
    static int coop_ok = -1;
    if (coop_ok < 0) {
        int maxb = 0;
        hipError_t qe =
            hipOccupancyMaxActiveBlocksPerMultiprocessor(&maxb, eik_persist, 256, 0);
        coop_ok = (qe == hipSuccess && maxb >= 4) ? 1 : 0;   // need 4 blocks/CU x 256 CUs
    }

    if (coop_ok) {
        void* args[] = {(void*)&uA, (void*)&uB, (void*)&fP, (void*)&out, (void*)&flags};
        hipError_t e = hipLaunchCooperativeKernel((void*)eik_persist,
                                                  dim3(1, NBY, NBZ), dim3(32, 8, 1),
                                                  args, 0, stream);
        if (e == hipSuccess) return;
    }

    // fallback: proven 128-launch ping-pong
    const dim3 block(32, 8, 1);
    const dim3 grid(1, 16, 128);
    for (int i = 1; i <= NITER; ++i) {
        const float* in = (i & 1) ? uA : uB;
        float* o        = (i & 1) ? uB : uA;
        eik_step<<<grid, block, 0, stream>>>(in, fP, o, i);
    }
    eik_extract<<<GN * GN * GN / 4 / 256, 256, 0, stream>>>(uA, out);
}

// Round 2
// 725.136 us; speedup vs baseline: 1.0054x; 1.0054x over previous
//
#include <hip/hip_runtime.h>

#define GN    128
#define GBIG  1.0e5f
#define NITER 128

// Padded layout: x pitch 128, y and z padded to 130 with BIG boundary planes.
#define PPY     130
#define PITCH_Y 128
#define PITCH_Z (128 * 130)
#define PADDED_TOTAL (130 * 130 * 128)

// Persistent-kernel block grid: tile 128 x 8 x 2  ->  16 x 64 blocks
#define NBY  16
#define NBZ  64
#define NBLK (NBY * NBZ)

typedef float fx4 __attribute__((ext_vector_type(4)));
typedef int   ix4 __attribute__((ext_vector_type(4)));

// ---------------------------------------------------------------------------
// init: padded uA, uB, fP + inbox lines.
// inbox[b][0..3] = iteration published by the {-y,+y,-z,+z} producer of b.
// Missing producer => NITER (never gates). 64B per block (one cacheline).
// ---------------------------------------------------------------------------
__global__ __launch_bounds__(256) void eik_init(const float* __restrict__ u0,
                                                const float* __restrict__ f,
                                                float* __restrict__ uA,
                                                float* __restrict__ uB,
                                                float* __restrict__ fP,
                                                int* __restrict__ inbox) {
    const int i = blockIdx.x * 256 + threadIdx.x;
    if (i < NBLK * 16) {
        const int b = i >> 4, d = i & 15;
        const int by = b % NBY, bz = b / NBY;
        int v = 0;
        if ((d == 0 && by == 0) || (d == 1 && by == NBY - 1) ||
            (d == 2 && bz == 0) || (d == 3 && bz == NBZ - 1))
            v = NITER;
        inbox[i] = v;
    }
    if (i >= PADDED_TOTAL) return;
    const int x = i & 127;
    const int r = i >> 7;          // r = z*130 + y
    const int y = r % 130;
    const int z = r / 130;
    float uv = GBIG, fv = 0.0f;
    if (y >= 1 && y <= GN && z >= 1 && z <= GN) {
        const int src = ((z - 1) * GN + (y - 1)) * GN + x;
        uv = u0[src];
        fv = f[src];
    }
    uA[i] = uv;
    uB[i] = uv;
    fP[i] = fv;
}

__device__ __forceinline__ float eik_solve(float ax, float ay, float az,
                                           float fh, float uc) {
    const float a1 = fminf(fminf(ax, ay), az);
    const float a3 = fmaxf(fmaxf(ax, ay), az);
    const float a2 = fmaxf(fminf(fmaxf(ax, ay), az), fminf(ax, ay));
    const float x1 = a1 + fh;
    const float d12 = a1 - a2;
    const float disc2 = 2.0f * fh * fh - d12 * d12;
    const float x2 = 0.5f * (a1 + a2 + sqrtf(fmaxf(disc2, 0.0f)));
    const float s = a1 + a2 + a3;
    const float q = a1 * a1 + a2 * a2 + a3 * a3;
    const float disc3 = s * s - 3.0f * (q - fh * fh);
    const float x3 = (s + sqrtf(fmaxf(disc3, 0.0f))) * (1.0f / 3.0f);
    const float xv = (x1 <= a2) ? x1 : ((x2 <= a3) ? x2 : x3);
    return fminf(uc, xv);
}

__device__ __forceinline__ void pub(int* box, int byteOff, int val) {
    asm volatile("global_store_dword %0, %1, %2 sc0 sc1"
                 :: "v"(byteOff), "v"(val), "s"(box) : "memory");
}

// ---------------------------------------------------------------------------
// persistent cooperative kernel: all 128 sweeps in one dispatch.
// Protocol (inbox value = i from producer P to consumer C):
//   "P has stored its u_i edge cells toward C (or they are act-culled), and
//    P's reading wave(s) for that edge have finished round-i reads."
// RAW: C at round i+1 waits inbox >= i before reading P's edge.  WAR: P's
// round i+2 writes buf[i&1]; gated by C's inbox >= i+1 whose publishing wave
// is exactly the wave that reads P's edge.  Direction culling: C skips
// waiting on a face whose adjacent cells are all inactive (d > i) -- those
// cells are act-culled so nothing stale is ever stored, and C's own edge
// toward P is likewise unstored, so P's skipped WAR is void.
// ---------------------------------------------------------------------------
__global__ __launch_bounds__(256, 4) void eik_persist(float* __restrict__ uA,
                                                      float* __restrict__ uB,
                                                      const float* __restrict__ fP,
                                                      float* __restrict__ out,
                                                      int* __restrict__ inbox) {
    const int lx = threadIdx.x;        // 0..31, 4 x-cells each
    const int ty = threadIdx.y;        // 0..7
    const int by = blockIdx.y;         // 0..15
    const int bz = blockIdx.z;         // 0..63
    const int tid = ty * 32 + lx;
    const int gy  = by * 8 + ty;       // 0..127
    const int gz0 = bz * 2;            // plane pair gz0, gz0+1
    const int x0  = lx * 4;

    // per-cell act distances
    const int dxm = (x0 <= 64 && 64 <= x0 + 3) ? 0
                                               : min(abs(x0 - 64), abs(x0 + 3 - 64));
    const int dy = abs(gy - 64);
    const int d0 = dxm + dy + abs(gz0 - 64);
    const int d1 = dxm + dy + abs(gz0 + 1 - 64);
    const int dmin01 = min(d0, d1);

    // block distances
    const int ry0 = by * 8, ry1 = ry0 + 7;
    const int dymin = (ry0 > 64) ? (ry0 - 64) : ((ry1 < 64) ? (64 - ry1) : 0);
    const int dzmin = min(abs(gz0 - 64), abs(gz0 + 1 - 64));
    const int start = max(1, dymin + dzmin);
    // per-face gating distances (x always spans the source column -> +0)
    const int dYm = abs(ry0 - 64) + dzmin;       // face row y=0   (slot 0)
    const int dYp = abs(ry1 - 64) + dzmin;       // face row y=7   (slot 1)
    const int dZm = abs(gz0 - 64) + dymin;       // face plane 0   (slot 2)
    const int dZp = abs(gz0 + 1 - 64) + dymin;   // face plane 1   (slot 3)

    const int idx = bz * NBY + by;
    const int inbOff = idx * 64;
    const int pubYp = (idx + 1) * 64 + 0;     // +y dependent, reads our row 7
    const int pubYm = (idx - 1) * 64 + 4;     // -y dependent, reads our row 0
    const int pubZp = (idx + NBY) * 64 + 8;   // +z dependent, reads our plane 1
    const int pubZm = (idx - NBY) * 64 + 12;  // -z dependent, reads our plane 0

    if (tid == 0 && start > 1) {   // pre-publish: u_{start-1} == u_0 everywhere here
        const int pv = start - 1;
        if (by < NBY - 1) pub(inbox, pubYp, pv);
        if (by > 0)       pub(inbox, pubYm, pv);
        if (bz < NBZ - 1) pub(inbox, pubZp, pv);
        if (bz > 0)       pub(inbox, pubZm, pv);
    }

    const int base0 = ((gz0 + 1) * PPY + (gy + 1)) * PITCH_Y + x0;
    const int base1 = base0 + PITCH_Z;
    const int vo0  = base0 * 4;
    const int vo1  = base1 * 4;
    const int vozm = vo0 - PITCH_Z * 4;
    const int vozp = vo1 + PITCH_Z * 4;

    fx4 c0 = *(const fx4*)(uA + base0);
    fx4 c1 = *(const fx4*)(uA + base1);
    const fx4 f0 = *(const fx4*)(fP + base0);
    const fx4 f1 = *(const fx4*)(fP + base1);

    for (int i = start; i <= NITER; ++i) {
        // ---- single-load inbox spin with per-direction targets ----
        const int tYm = (dYm <= i) ? i - 1 : -0x40000000;
        const int tYp = (dYp <= i) ? i - 1 : -0x40000000;
        const int tZm = (dZm <= i) ? i - 1 : -0x40000000;
        const int tZp = (dZp <= i) ? i - 1 : -0x40000000;
        int sp = 0;
        for (;;) {
            ix4 v;
            asm volatile("global_load_dwordx4 %0, %1, %2 sc0 sc1\n\t"
                         "s_waitcnt vmcnt(0)"
                         : "=&v"(v) : "v"(inbOff), "s"(inbox) : "memory");
            if (v.x >= tYm && v.y >= tYp && v.z >= tZm && v.w >= tZp) break;
            if (++sp < 4) __builtin_amdgcn_s_sleep(1);
            else          __builtin_amdgcn_s_sleep(10);
        }

        // ---- x-neighbors: shuffles unconditional (exec-masked sources are UB) ----
        float xm0 = __shfl_up(c0.w, 1);   if (lx == 0)  xm0 = GBIG;
        float xp0 = __shfl_down(c0.x, 1); if (lx == 31) xp0 = GBIG;
        float xm1 = __shfl_up(c1.w, 1);   if (lx == 0)  xm1 = GBIG;
        float xp1 = __shfl_down(c1.x, 1); if (lx == 31) xp1 = GBIG;

        const bool run = (dmin01 <= i);   // any of this thread's 8 cells live?
        fx4 n0, n1;
        if (run) {
            const float* S = (i & 1) ? uA : uB;
            fx4 ym0, yp0, ym1, yp1, zm, zp;
            asm volatile(
                "global_load_dwordx4 %0, %6, %10 offset:-512 sc0 sc1\n\t"
                "global_load_dwordx4 %1, %6, %10 offset:512 sc0 sc1\n\t"
                "global_load_dwordx4 %2, %7, %10 offset:-512 sc0 sc1\n\t"
                "global_load_dwordx4 %3, %7, %10 offset:512 sc0 sc1\n\t"
                "global_load_dwordx4 %4, %8, %10 sc0 sc1\n\t"
                "global_load_dwordx4 %5, %9, %10 sc0 sc1\n\t"
                "s_waitcnt vmcnt(0)"
                : "=&v"(ym0), "=&v"(yp0), "=&v"(ym1), "=&v"(yp1), "=&v"(zm), "=&v"(zp)
                : "v"(vo0), "v"(vo1), "v"(vozm), "v"(vozp), "s"(S)
                : "memory");

            n0.x = eik_solve(fminf(xm0,  c0.y), fminf(ym0.x, yp0.x), fminf(zm.x, c1.x), f0.x, c0.x);
            n0.y = eik_solve(fminf(c0.x, c0.z), fminf(ym0.y, yp0.y), fminf(zm.y, c1.y), f0.y, c0.y);
            n0.z = eik_solve(fminf(c0.y, c0.w), fminf(ym0.z, yp0.z), fminf(zm.z, c1.z), f0.z, c0.z);
            n0.w = eik_solve(fminf(c0.z, xp0),  fminf(ym0.w, yp0.w), fminf(zm.w, c1.w), f0.w, c0.w);
            n1.x = eik_solve(fminf(xm1,  c1.y), fminf(ym1.x, yp1.x), fminf(c0.x, zp.x), f1.x, c1.x);
            n1.y = eik_solve(fminf(c1.x, c1.z), fminf(ym1.y, yp1.y), fminf(c0.y, zp.y), f1.y, c1.y);
            n1.z = eik_solve(fminf(c1.y, c1.w), fminf(ym1.z, yp1.z), fminf(c0.z, zp.z), f1.z, c1.z);
            n1.w = eik_solve(fminf(c1.z, xp1),  fminf(ym1.w, yp1.w), fminf(c0.w, zp.w), f1.w, c1.w);
        }

        if (i < NITER) {
            float* D = (i & 1) ? uB : uA;
            if (run) {
                if (d0 <= i) {
                    c0 = n0;
                    asm volatile("global_store_dwordx4 %0, %1, %2 sc0 sc1"
                                 :: "v"(vo0), "v"(c0), "s"(D) : "memory");
                }
                if (d1 <= i) {
                    c1 = n1;
                    asm volatile("global_store_dwordx4 %0, %1, %2 sc0 sc1"
                                 :: "v"(vo1), "v"(c1), "s"(D) : "memory");
                }
            }
            asm volatile("s_waitcnt vmcnt(0)" ::: "memory");   // per-wave drain
            // early y-publishes: edge row is owned by the publishing wave
            if (tid == 0 && by > 0)         pub(inbox, pubYm, i);
            if (tid == 224 && by < NBY - 1) pub(inbox, pubYp, i);
            __syncthreads();                                    // all planes stored
            if (tid == 0) {
                if (bz > 0)       pub(inbox, pubZm, i);
                if (bz < NBZ - 1) pub(inbox, pubZp, i);
            }
        } else {
            if (run) {
                if (d0 <= i) c0 = n0;
                if (d1 <= i) c1 = n1;
            }
        }
    }

    // fused extract: compact 128^3 output straight from registers
    float* o = out + (gz0 * GN + gy) * GN + x0;
    *(fx4*)o = c0;
    *(fx4*)(o + GN * GN) = c1;
}

// ---------------------------------------------------------------------------
// fallback path (proven 128-launch structure) if cooperative launch refused
// ---------------------------------------------------------------------------
__global__ __launch_bounds__(256) void eik_step(const float* __restrict__ uin,
                                                const float* __restrict__ fP,
                                                float* __restrict__ uout,
                                                int iter) {
    const int lx = threadIdx.x;
    const int gy = blockIdx.y * 8 + threadIdx.y;
    const int gz = blockIdx.z;
    const int x0 = 4 * lx;
    const int dxm = (x0 <= 64 && 64 <= x0 + 3)
                        ? 0
                        : min(abs(x0 - 64), abs(x0 + 3 - 64));
    const int d = dxm + abs(gy - 64) + abs(gz - 64);
    if (d > iter) return;

    const int y = gy + 1;
    const int z = gz + 1;
    const int base = (z * PPY + y) * PITCH_Y + x0;

    const float4 c  = *(const float4*)(uin + base);
    float xm_s = uin[base - 1];
    float xp_s = uin[base + 4];
    if (lx == 0)  xm_s = GBIG;
    if (lx == 31) xp_s = GBIG;
    const float4 ym = *(const float4*)(uin + base - PITCH_Y);
    const float4 yp = *(const float4*)(uin + base + PITCH_Y);
    const float4 zm = *(const float4*)(uin + base - PITCH_Z);
    const float4 zp = *(const float4*)(uin + base + PITCH_Z);
    const float4 f4 = *(const float4*)(fP + base);

    float4 res;
    res.x = eik_solve(fminf(xm_s, c.y), fminf(ym.x, yp.x), fminf(zm.x, zp.x), f4.x, c.x);
    res.y = eik_solve(fminf(c.x, c.z), fminf(ym.y, yp.y), fminf(zm.y, zp.y), f4.y, c.y);
    res.z = eik_solve(fminf(c.y, c.w), fminf(ym.z, yp.z), fminf(zm.z, zp.z), f4.z, c.z);
    res.w = eik_solve(fminf(c.z, xp_s), fminf(ym.w, yp.w), fminf(zm.w, zp.w), f4.w, c.w);

    *(float4*)(uout + base) = res;
}

__global__ __launch_bounds__(256) void eik_extract(const float* __restrict__ uf,
                                                   float* __restrict__ out) {
    const int j = blockIdx.x * 256 + threadIdx.x;
    const int x4 = j & 31;
    const int y  = (j >> 5) & 127;
    const int z  = j >> 12;
    const float4 v =
        *(const float4*)(uf + ((z + 1) * PPY + (y + 1)) * PITCH_Y + 4 * x4);
    *(float4*)(out + 4 * j) = v;
}

extern "C" void kernel_launch(void* const* d_in, const int* in_sizes, int n_in,
                              void* d_out, int out_size, void* d_ws, size_t ws_size,
                              hipStream_t stream) {
    const float* u0 = (const float*)d_in[0];
    const float* f  = (const float*)d_in[1];
    float* out = (float*)d_out;

    float* uA = (float*)d_ws;                    // 8.65 MB each
    float* uB = uA + PADDED_TOTAL;
    float* fP = uB + PADDED_TOTAL;
    int* inbox = (int*)(fP + PADDED_TOTAL);      // 64 KB padded inbox lines

    {
        const int nb = (PADDED_TOTAL + 255) / 256;
        eik_init<<<nb, 256, 0, stream>>>(u0, f, uA, uB, fP, inbox);
    }

    static int coop_ok = -1;
    if (coop_ok < 0) {
        int maxb = 0;
        hipError_t qe =
            hipOccupancyMaxActiveBlocksPerMultiprocessor(&maxb, eik_persist, 256, 0);
        coop_ok = (qe == hipSuccess && maxb >= 4) ? 1 : 0;
    }

    if (coop_ok) {
        void* args[] = {(void*)&uA, (void*)&uB, (void*)&fP, (void*)&out, (void*)&inbox};
        hipError_t e = hipLaunchCooperativeKernel((void*)eik_persist,
                                                  dim3(1, NBY, NBZ), dim3(32, 8, 1),
                                                  args, 0, stream);
        if (e == hipSuccess) return;
    }

    const dim3 block(32, 8, 1);
    const dim3 grid(1, 16, 128);
    for (int i = 1; i <= NITER; ++i) {
        const float* in = (i & 1) ? uA : uB;
        float* o        = (i & 1) ? uB : uA;
        eik_step<<<grid, block, 0, stream>>>(in, fP, o, i);
    }
    eik_extract<<<GN * GN * GN / 4 / 256, 256, 0, stream>>>(uA, out);
}